// Round 10
// baseline (802.512 us; speedup 1.0000x reference)
//
#include <hip/hip_runtime.h>

// LDS row pitch in ushorts: 136*2=272B -> dword stride 68 -> bank step 4 ->
// only 2-way aliasing (free). 272 is a multiple of 16 -> rows stay 16B-aligned.
#define P 136

typedef __attribute__((ext_vector_type(8))) short short8;
typedef __attribute__((ext_vector_type(4))) float f32x4;

__device__ __forceinline__ unsigned short f2bf(float f) {
  union { float f; unsigned u; } v; v.f = f;
  unsigned u = v.u + 0x7fffu + ((v.u >> 16) & 1u);   // RNE
  return (unsigned short)(u >> 16);
}
__device__ __forceinline__ float bf2f(unsigned short h) {
  union { unsigned u; float f; } v; v.u = ((unsigned)h) << 16;
  return v.f;
}
// pack two floats -> bf16x2 dword in 3 VALU ops (round-half-away + v_perm).
__device__ __forceinline__ unsigned pack2bf(float x, float y) {
  union { float f; unsigned u; } a, b; a.f = x; b.f = y;
  return __builtin_amdgcn_perm(b.u + 0x8000u, a.u + 0x8000u, 0x07060302u);
}
// silu via hw approx rcp (rel err ~1e-7 << bf16 rounding).
__device__ __forceinline__ float silu_f(float x) {
  float e = __expf(-x);
  return x * __builtin_amdgcn_rcpf(1.0f + e);
}

// Transposed-GEMM building blocks. D[m=feat][n=row]:
//   A = W^T [feat][k] in REGISTERS; B = X [row][k] in LDS (b128 reads).
__device__ __forceinline__ void load_A128(const unsigned short* __restrict__ W,
                                          int m0w, int l16, int q, short8 a[2][4]) {
#pragma unroll
  for (int rt = 0; rt < 2; ++rt)
#pragma unroll
    for (int kt = 0; kt < 4; ++kt)
      a[rt][kt] = *(const short8*)&W[(m0w + rt * 16 + l16) * 128 + kt * 32 + q * 8];
}

__device__ __forceinline__ void gemm_T(const short8 a[2][4],
                                       const unsigned short* sB,
                                       int l16, int q, f32x4 acc[2][8]) {
#pragma unroll
  for (int kt = 0; kt < 4; ++kt)
#pragma unroll
    for (int ct = 0; ct < 8; ++ct) {
      short8 b = *(const short8*)&sB[(ct * 16 + l16) * P + kt * 32 + q * 8];
      acc[0][ct] = __builtin_amdgcn_mfma_f32_16x16x32_bf16(a[0][kt], b, acc[0][ct], 0, 0, 0);
      acc[1][ct] = __builtin_amdgcn_mfma_f32_16x16x32_bf16(a[1][kt], b, acc[1][ct], 0, 0, 0);
    }
}

template <bool SILU>
__device__ __forceinline__ void epilogue_T(const f32x4 acc[2][8], const float* bias,
                                           unsigned short* sOut, int m0w, int l16,
                                           int q) {
#pragma unroll
  for (int rt = 0; rt < 2; ++rt) {
    int f0 = m0w + rt * 16 + q * 4;
    float4 bv = *(const float4*)&bias[f0];   // bias arrays are __align__(16)
#pragma unroll
    for (int ct = 0; ct < 8; ++ct) {
      float v0 = acc[rt][ct][0] + bv.x, v1 = acc[rt][ct][1] + bv.y;
      float v2 = acc[rt][ct][2] + bv.z, v3 = acc[rt][ct][3] + bv.w;
      if (SILU) { v0 = silu_f(v0); v1 = silu_f(v1); v2 = silu_f(v2); v3 = silu_f(v3); }
      uint2 w; w.x = pack2bf(v0, v1); w.y = pack2bf(v2, v3);
      *(uint2*)&sOut[(ct * 16 + l16) * P + f0] = w;
    }
  }
}

// ---------------------------------------------------------------------------
// Merged fold + hist kernel (256 threads):
//   blocks [0,64):  weight folding
//   blocks [64,..): 8-way-replicated histogram of tgt, int4 reads (4 edges/thr)
// Copy index = (e>>10)&7 — deterministic, identical in the scatter pass.
// ---------------------------------------------------------------------------
__global__ __launch_bounds__(256) void fold_hist_kernel(
    const float* __restrict__ nw1, const float* __restrict__ nw2,
    const float* __restrict__ nb2, const float* __restrict__ ew2,
    const float* __restrict__ eb2, const float* __restrict__ mw1,
    const float* __restrict__ mb1, const float* __restrict__ mw2,
    const float* __restrict__ uw1, const float* __restrict__ uw2,
    const float* __restrict__ ew1,
    unsigned short* __restrict__ nw1t, unsigned short* __restrict__ wnt,
    unsigned short* __restrict__ wct, unsigned short* __restrict__ mw2t,
    unsigned short* __restrict__ uw1t, unsigned short* __restrict__ uw2t,
    unsigned short* __restrict__ ew1t8,
    float* __restrict__ bn, float* __restrict__ bc,
    const int* __restrict__ eidx, int* __restrict__ hist8, int E, int G) {
  if (blockIdx.x >= 64) {
    int chunk = blockIdx.x - 64;
    int e0 = chunk * 1024 + threadIdx.x * 4;
    int* h = hist8 + (size_t)(chunk & 7) * G;
    if (e0 + 3 < E) {
      int4 t4 = *(const int4*)&eidx[E + e0];
      atomicAdd(&h[t4.x], 1);
      atomicAdd(&h[t4.y], 1);
      atomicAdd(&h[t4.z], 1);
      atomicAdd(&h[t4.w], 1);
    } else {
      for (int k = 0; k < 4; ++k)
        if (e0 + k < E) atomicAdd(&h[eidx[E + e0 + k]], 1);
    }
    return;
  }
  int b = blockIdx.x * 2 + (threadIdx.x >> 7);  // output col
  int t = threadIdx.x & 127;                    // input row
  float accn = 0.f, accc = 0.f;
  for (int j = 0; j < 128; ++j) {
    accn += nw2[t * 128 + j] * mw1[j * 128 + b];
    accc += ew2[t * 128 + j] * mw1[(128 + j) * 128 + b];
  }
  wnt[b * 128 + t] = f2bf(accn);
  wct[b * 128 + t] = f2bf(accc);
  nw1t[b * 128 + t] = f2bf(nw1[t * 128 + b]);
  mw2t[b * 128 + t] = f2bf(mw2[t * 128 + b]);
  uw1t[b * 128 + t] = f2bf(uw1[t * 128 + b]);
  uw2t[b * 128 + t] = f2bf(uw2[t * 128 + b]);
  if (t < 8) ew1t8[b * 8 + t] = (t < 6) ? f2bf(ew1[t * 128 + b]) : (unsigned short)0;
  if (b == 0) {
    float sn = 0.f, sc = 0.f;
    for (int j = 0; j < 128; ++j) {
      sn += nb2[j] * mw1[j * 128 + t];
      sc += eb2[j] * mw1[(128 + j) * 128 + t];
    }
    bn[t] = sn;
    bc[t] = mb1[t] + sc;
  }
}

// ---------------------------------------------------------------------------
// 8-way scan: global offsets per (cell, copy) + dense per-cell counts.
// ---------------------------------------------------------------------------
__global__ __launch_bounds__(1024) void scan8_kernel(const int* __restrict__ hist8,
                                                     int* __restrict__ cursor8,
                                                     int* __restrict__ counts, int G) {
  __shared__ int s[1024];
  int tid = threadIdx.x;
  int per = (G + 1023) >> 10;
  int b0 = tid * per;
  int sum = 0;
  for (int i = 0; i < per; ++i) {
    int cell = b0 + i;
    if (cell < G) {
#pragma unroll
      for (int c = 0; c < 8; ++c) sum += hist8[c * G + cell];
    }
  }
  s[tid] = sum;
  __syncthreads();
  for (int off = 1; off < 1024; off <<= 1) {
    int v = (tid >= off) ? s[tid - off] : 0;
    __syncthreads();
    s[tid] += v;
    __syncthreads();
  }
  int run = s[tid] - sum;  // exclusive prefix over this thread's cells
  for (int i = 0; i < per; ++i) {
    int cell = b0 + i;
    if (cell < G) {
      int pre = run;
#pragma unroll
      for (int c = 0; c < 8; ++c) {
        int v = hist8[c * G + cell];
        cursor8[c * G + cell] = pre;
        pre += v;
      }
      counts[cell] = pre - run;
      run = pre;
    }
  }
}

// ---------------------------------------------------------------------------
// Merged scatter + node kernel (256 threads):
//   blocks [0,nScat):   scatter 4 edges/thread into sorted position using the
//                       8-way cursor copy (e>>10)&7 — matches hist pass exactly
//   blocks [nScat,..):  node MLP: node_pre = silu(x@nw1+nb1) @ Wn + bn
// ---------------------------------------------------------------------------
__global__ __launch_bounds__(256, 3) void scatter_node_kernel(
    const int* __restrict__ eidx, int* __restrict__ cursor8,
    int2* __restrict__ st, int E, int G, int nScat,
    const float* __restrict__ x, const float* __restrict__ nb1,
    const unsigned short* __restrict__ nw1t, const unsigned short* __restrict__ wnt,
    const float* __restrict__ bn, unsigned short* __restrict__ node_pre, int N) {
  __shared__ __align__(16) unsigned short s_x[128 * P];
  __shared__ __align__(16) float s_b1[128];
  __shared__ __align__(16) float s_bn[128];

  if (blockIdx.x < (unsigned)nScat) {
    int chunk = blockIdx.x;
    int e0 = chunk * 1024 + threadIdx.x * 4;
    int* cur = cursor8 + (size_t)(chunk & 7) * G;
    if (e0 + 3 < E) {
      int4 s4 = *(const int4*)&eidx[e0];
      int4 t4 = *(const int4*)&eidx[E + e0];
      int p0 = atomicAdd(&cur[t4.x], 1); st[p0] = make_int2(s4.x, t4.x);
      int p1 = atomicAdd(&cur[t4.y], 1); st[p1] = make_int2(s4.y, t4.y);
      int p2 = atomicAdd(&cur[t4.z], 1); st[p2] = make_int2(s4.z, t4.z);
      int p3 = atomicAdd(&cur[t4.w], 1); st[p3] = make_int2(s4.w, t4.w);
    } else {
      for (int k = 0; k < 4; ++k)
        if (e0 + k < E) {
          int tg = eidx[E + e0 + k];
          int pos = atomicAdd(&cur[tg], 1);
          st[pos] = make_int2(eidx[e0 + k], tg);
        }
    }
    return;
  }

  int tid = threadIdx.x;
  long base = (long)(blockIdx.x - nScat) * 128;

#pragma unroll
  for (int i = 0; i < 16; ++i) {
    int flat = tid + i * 256;      // 4096 float4 = 128 rows x 32
    int row = flat >> 5;
    int c4 = (flat & 31) << 2;
    float4 v = make_float4(0.f, 0.f, 0.f, 0.f);
    if (base + row < N) v = *(const float4*)&x[(base + row) * 128 + c4];
    uint2 w; w.x = pack2bf(v.x, v.y); w.y = pack2bf(v.z, v.w);
    *(uint2*)&s_x[row * P + c4] = w;
  }
  if (tid < 128) { s_b1[tid] = nb1[tid]; s_bn[tid] = bn[tid]; }
  __syncthreads();

  int wave = tid >> 6, lane = tid & 63;
  int q = lane >> 4, l16 = lane & 15;
  int m0w = wave * 32;

  short8 a1[2][4];
  load_A128(nw1t, m0w, l16, q, a1);
  f32x4 acc[2][8];
#pragma unroll
  for (int rt = 0; rt < 2; ++rt)
#pragma unroll
    for (int ct = 0; ct < 8; ++ct) acc[rt][ct] = (f32x4){0.f, 0.f, 0.f, 0.f};
  gemm_T(a1, s_x, l16, q, acc);
  __syncthreads();
  epilogue_T<true>(acc, s_b1, s_x, m0w, l16, q);
  __syncthreads();

  short8 a2[2][4];
  load_A128(wnt, m0w, l16, q, a2);
#pragma unroll
  for (int rt = 0; rt < 2; ++rt)
#pragma unroll
    for (int ct = 0; ct < 8; ++ct) acc[rt][ct] = (f32x4){0.f, 0.f, 0.f, 0.f};
  gemm_T(a2, s_x, l16, q, acc);

  // store node_pre[node][feat] packed 8B
#pragma unroll
  for (int rt = 0; rt < 2; ++rt) {
    int f0 = m0w + rt * 16 + q * 4;
    float4 bv = *(const float4*)&s_bn[f0];
#pragma unroll
    for (int ct = 0; ct < 8; ++ct) {
      long n = base + ct * 16 + l16;
      if (n < N) {
        uint2 w;
        w.x = pack2bf(acc[rt][ct][0] + bv.x, acc[rt][ct][1] + bv.y);
        w.y = pack2bf(acc[rt][ct][2] + bv.z, acc[rt][ct][3] + bv.w);
        *(uint2*)&node_pre[n * 128 + f0] = w;
      }
    }
  }
}

// ---------------------------------------------------------------------------
// Edge kernel (sorted edges, transposed GEMMs), 128 edges / 256 threads.
// Unchanged from R9 (counters should replicate exactly).
// ---------------------------------------------------------------------------
__global__ __launch_bounds__(256, 3) void edge_kernel(
    const int2* __restrict__ st_sorted, const float* __restrict__ node_pos,
    const float* __restrict__ grid_pos, const float* __restrict__ ori,
    const unsigned short* __restrict__ ew1t8, const float* __restrict__ eb1,
    const unsigned short* __restrict__ wct, const float* __restrict__ bc,
    const unsigned short* __restrict__ node_pre, float* __restrict__ sums, int E) {
  __shared__ __align__(16) unsigned short s_h[128 * P];
  __shared__ int s_src[128];
  __shared__ int s_tgt[128];
  __shared__ __align__(16) float s_eb1[128];
  __shared__ __align__(16) float s_bc[128];

  int tid = threadIdx.x;
  int base = blockIdx.x * 128;

  if (tid < 128) {
    s_eb1[tid] = eb1[tid];
    s_bc[tid] = bc[tid];
    int eg = base + tid;
    int s = 0, tg = -1;
    float a0 = 0.f, a1 = 0.f, a2 = 0.f, a3 = 0.f, a4 = 0.f, a5 = 0.f;
    if (eg < E) {
      int2 st = st_sorted[eg];
      s = st.x; tg = st.y;
      float2 p01 = *(const float2*)&node_pos[s * 3];
      float pz = node_pos[s * 3 + 2];
      float2 g01 = *(const float2*)&grid_pos[tg * 3];
      float gz = grid_pos[tg * 3 + 2];
      float4 o0 = *(const float4*)&ori[(long)s * 9];      // o[0..3]
      float4 o1 = *(const float4*)&ori[(long)s * 9 + 4];  // o[4..7]
      float o8 = ori[(long)s * 9 + 8];
      float rx = g01.x - p01.x, ry = g01.y - p01.y, rz = gz - pz;
      a0 = p01.x; a1 = p01.y; a2 = pz;
      a3 = rx * o0.x + ry * o0.w + rz * o1.z;
      a4 = rx * o0.y + ry * o1.x + rz * o1.w;
      a5 = rx * o0.z + ry * o1.y + rz * o8;
    }
    s_src[tid] = s;
    s_tgt[tid] = tg;
    uint4 w0;
    w0.x = pack2bf(a0, a1); w0.y = pack2bf(a2, a3); w0.z = pack2bf(a4, a5); w0.w = 0u;
    *(uint4*)&s_h[tid * P] = w0;   // attr row [edge][k0..7]
  }
  __syncthreads();

  int wave = tid >> 6, lane = tid & 63;
  int q = lane >> 4, l16 = lane & 15;
  int m0w = wave * 32;
  short8 z8 = (short8){0, 0, 0, 0, 0, 0, 0, 0};

  short8 awc[2][4];
  load_A128(wct, m0w, l16, q, awc);

  short8 ae0 = z8, ae1 = z8;
  if (q == 0) {
    ae0 = *(const short8*)&ew1t8[(m0w + l16) * 8];
    ae1 = *(const short8*)&ew1t8[(m0w + 16 + l16) * 8];
  }

  // GEMM0: D[h][edge] = ew1^T · attr^T
  f32x4 acc0[2][8];
#pragma unroll
  for (int rt = 0; rt < 2; ++rt)
#pragma unroll
    for (int ct = 0; ct < 8; ++ct) acc0[rt][ct] = (f32x4){0.f, 0.f, 0.f, 0.f};
#pragma unroll
  for (int ct = 0; ct < 8; ++ct) {
    short8 b = z8;
    if (q == 0) b = *(const short8*)&s_h[(ct * 16 + l16) * P];
    acc0[0][ct] = __builtin_amdgcn_mfma_f32_16x16x32_bf16(ae0, b, acc0[0][ct], 0, 0, 0);
    acc0[1][ct] = __builtin_amdgcn_mfma_f32_16x16x32_bf16(ae1, b, acc0[1][ct], 0, 0, 0);
  }
  __syncthreads();

  epilogue_T<true>(acc0, s_eb1, s_h, m0w, l16, q);   // h1 -> s_h[edge][feat]
  __syncthreads();

  // acc := node_pre[src[edge]][feat]  via identity-A MFMA (b128 gathers)
  short8 aI;
#pragma unroll
  for (int j = 0; j < 8; ++j)
    aI[j] = ((q * 8 + j) == l16) ? (short)0x3F80 : (short)0;
  f32x4 acc[2][8];
#pragma unroll
  for (int ct = 0; ct < 8; ++ct) {
    long srow = (long)s_src[ct * 16 + l16] * 128;
#pragma unroll
    for (int rt = 0; rt < 2; ++rt) {
      short8 bnp = z8;
      if (q < 2) bnp = *(const short8*)&node_pre[srow + m0w + rt * 16 + q * 8];
      acc[rt][ct] = __builtin_amdgcn_mfma_f32_16x16x32_bf16(
          aI, bnp, (f32x4){0.f, 0.f, 0.f, 0.f}, 0, 0, 0);
    }
  }

  // GEMM1: acc += Wc^T · h1^T
  gemm_T(awc, s_h, l16, q, acc);
  __syncthreads();

  epilogue_T<true>(acc, s_bc, s_h, m0w, l16, q);     // h2 -> s_h[edge][feat]
  __syncthreads();

  // segmented reduction: thread = (colpair, 32-row chunk); flush per run.
  {
    int cp = tid & 63;
    int chunk = tid >> 6;
    int c0 = cp * 2;
    int row0 = chunk * 32;
    float v0 = 0.f, v1 = 0.f;
    int cur = s_tgt[row0];
    for (int r = 0; r < 32; ++r) {
      int row = row0 + r;
      int tg = s_tgt[row];
      if (tg != cur) {
        if (cur >= 0) {
          atomicAdd(&sums[(long)cur * 128 + c0], v0);
          atomicAdd(&sums[(long)cur * 128 + c0 + 1], v1);
        }
        v0 = 0.f; v1 = 0.f; cur = tg;
      }
      unsigned w = *(const unsigned*)&s_h[row * P + c0];
      v0 += bf2f((unsigned short)w);
      v1 += bf2f((unsigned short)(w >> 16));
    }
    if (cur >= 0) {
      atomicAdd(&sums[(long)cur * 128 + c0], v0);
      atomicAdd(&sums[(long)cur * 128 + c0 + 1], v1);
    }
  }
}

// ---------------------------------------------------------------------------
// Grid kernel (transposed): x = sums/clip(counts,1); y = x@mw2+mb2;
// out = silu(y@uw1+ub1)@uw2 + ub2.  Final store: packed float4.
// ---------------------------------------------------------------------------
__global__ __launch_bounds__(256, 3) void grid_kernel(
    const float* __restrict__ sums, const int* __restrict__ counts,
    const float* __restrict__ mb2, const float* __restrict__ ub1,
    const float* __restrict__ ub2, const unsigned short* __restrict__ mw2t,
    const unsigned short* __restrict__ uw1t, const unsigned short* __restrict__ uw2t,
    float* __restrict__ out, int G) {
  __shared__ __align__(16) unsigned short s_x[128 * P];
  __shared__ __align__(16) float s_bm[128];
  __shared__ __align__(16) float s_b1[128];
  __shared__ __align__(16) float s_b2[128];
  int tid = threadIdx.x;
  long base = (long)blockIdx.x * 128;

#pragma unroll
  for (int i = 0; i < 16; ++i) {
    int flat = tid + i * 256;       // 4096 float4 = 128 rows x 32
    int row = flat >> 5;
    int c4 = (flat & 31) << 2;
    float4 v = make_float4(0.f, 0.f, 0.f, 0.f);
    float inv = 1.f;
    if (base + row < G) {
      v = *(const float4*)&sums[(base + row) * 128 + c4];
      int c = counts[base + row];
      inv = __builtin_amdgcn_rcpf((float)(c < 1 ? 1 : c));
    }
    uint2 w; w.x = pack2bf(v.x * inv, v.y * inv); w.y = pack2bf(v.z * inv, v.w * inv);
    *(uint2*)&s_x[row * P + c4] = w;
  }
  if (tid < 128) { s_bm[tid] = mb2[tid]; s_b1[tid] = ub1[tid]; s_b2[tid] = ub2[tid]; }
  __syncthreads();

  int wave = tid >> 6, lane = tid & 63;
  int q = lane >> 4, l16 = lane & 15;
  int m0w = wave * 32;

  f32x4 acc[2][8];
  short8 aw[2][4];

  // GEMM A: grid_feat = x@mw2 + mb2 (no activation)
  load_A128(mw2t, m0w, l16, q, aw);
#pragma unroll
  for (int rt = 0; rt < 2; ++rt)
#pragma unroll
    for (int ct = 0; ct < 8; ++ct) acc[rt][ct] = (f32x4){0.f, 0.f, 0.f, 0.f};
  gemm_T(aw, s_x, l16, q, acc);
  __syncthreads();
  epilogue_T<false>(acc, s_bm, s_x, m0w, l16, q);
  __syncthreads();

  // GEMM B: silu(y@uw1 + ub1)
  load_A128(uw1t, m0w, l16, q, aw);
#pragma unroll
  for (int rt = 0; rt < 2; ++rt)
#pragma unroll
    for (int ct = 0; ct < 8; ++ct) acc[rt][ct] = (f32x4){0.f, 0.f, 0.f, 0.f};
  gemm_T(aw, s_x, l16, q, acc);
  __syncthreads();
  epilogue_T<true>(acc, s_b1, s_x, m0w, l16, q);
  __syncthreads();

  // GEMM C: out = h@uw2 + ub2  (fp32 float4 stores)
  load_A128(uw2t, m0w, l16, q, aw);
#pragma unroll
  for (int rt = 0; rt < 2; ++rt)
#pragma unroll
    for (int ct = 0; ct < 8; ++ct) acc[rt][ct] = (f32x4){0.f, 0.f, 0.f, 0.f};
  gemm_T(aw, s_x, l16, q, acc);

#pragma unroll
  for (int rt = 0; rt < 2; ++rt) {
    int f0 = m0w + rt * 16 + q * 4;
    float4 bv = *(const float4*)&s_b2[f0];
#pragma unroll
    for (int ct = 0; ct < 8; ++ct) {
      long g = base + ct * 16 + l16;
      if (g < G) {
        float4 o = make_float4(acc[rt][ct][0] + bv.x, acc[rt][ct][1] + bv.y,
                               acc[rt][ct][2] + bv.z, acc[rt][ct][3] + bv.w);
        *(float4*)&out[g * 128 + f0] = o;
      }
    }
  }
}

extern "C" void kernel_launch(void* const* d_in, const int* in_sizes, int n_in,
                              void* d_out, int out_size, void* d_ws, size_t ws_size,
                              hipStream_t stream) {
  const float* x    = (const float*)d_in[0];
  const float* npos = (const float*)d_in[1];
  const float* gpos = (const float*)d_in[2];
  const int*   eidx = (const int*)d_in[3];
  const float* ori  = (const float*)d_in[4];
  const float* nw1 = (const float*)d_in[5];
  const float* nb1 = (const float*)d_in[6];
  const float* nw2 = (const float*)d_in[7];
  const float* nb2 = (const float*)d_in[8];
  const float* ew1 = (const float*)d_in[9];
  const float* eb1 = (const float*)d_in[10];
  const float* ew2 = (const float*)d_in[11];
  const float* eb2 = (const float*)d_in[12];
  const float* mw1 = (const float*)d_in[13];
  const float* mb1 = (const float*)d_in[14];
  const float* mw2 = (const float*)d_in[15];
  const float* mb2 = (const float*)d_in[16];
  const float* uw1 = (const float*)d_in[17];
  const float* ub1 = (const float*)d_in[18];
  const float* uw2 = (const float*)d_in[19];
  const float* ub2 = (const float*)d_in[20];

  int N = in_sizes[0] / 128;
  int G = in_sizes[2] / 3;
  int E = in_sizes[3] / 2;

  // ws layout (proven ~43 MB footprint).
  char* ws = (char*)d_ws;
  size_t off = 0;
  float* sums = (float*)(ws + off);            off += (size_t)G * 128 * 4;
  int* counts = (int*)(ws + off);              off += (size_t)G * 4;
  unsigned short* node_pre = (unsigned short*)(ws + off); off += (size_t)N * 128 * 2;
  off = (off + 255) & ~(size_t)255;
  unsigned short* w_nw1t = (unsigned short*)(ws + off); off += 128 * 128 * 2;
  unsigned short* w_wnt  = (unsigned short*)(ws + off); off += 128 * 128 * 2;
  unsigned short* w_wct  = (unsigned short*)(ws + off); off += 128 * 128 * 2;
  unsigned short* w_mw2t = (unsigned short*)(ws + off); off += 128 * 128 * 2;
  unsigned short* w_uw1t = (unsigned short*)(ws + off); off += 128 * 128 * 2;
  unsigned short* w_uw2t = (unsigned short*)(ws + off); off += 128 * 128 * 2;
  unsigned short* w_ew1t8 = (unsigned short*)(ws + off); off += 128 * 8 * 2;
  float* bn = (float*)(ws + off); off += 128 * 4;
  float* bc = (float*)(ws + off); off += 128 * 4;

  // d_out scratch (16.78 MB): st_sorted (8 MB) + hist8 (1 MB) + cursor8 (1 MB).
  // All dead before grid_kernel overwrites d_out; stream order makes it safe.
  char* ob = (char*)d_out;
  int2* st_sorted = (int2*)ob;
  int* hist8 = (int*)(ob + (size_t)E * 8);
  int* cursor8 = hist8 + 8 * (size_t)G;

  int nChunk = (E + 1023) / 1024;   // 4 edges/thread, 256 threads
  int nNode = (N + 127) / 128;

  // zero sums + counts (contiguous, in ws) and hist8 (in d_out)
  hipMemsetAsync(sums, 0, ((size_t)G * 128 + G) * 4, stream);
  hipMemsetAsync(hist8, 0, 8 * (size_t)G * 4, stream);

  fold_hist_kernel<<<64 + nChunk, 256, 0, stream>>>(
      nw1, nw2, nb2, ew2, eb2, mw1, mb1, mw2, uw1, uw2, ew1,
      w_nw1t, w_wnt, w_wct, w_mw2t, w_uw1t, w_uw2t, w_ew1t8, bn, bc,
      eidx, hist8, E, G);
  scan8_kernel<<<1, 1024, 0, stream>>>(hist8, cursor8, counts, G);
  scatter_node_kernel<<<nChunk + nNode, 256, 0, stream>>>(
      eidx, cursor8, st_sorted, E, G, nChunk,
      x, nb1, w_nw1t, w_wnt, bn, node_pre, N);
  edge_kernel<<<(E + 127) / 128, 256, 0, stream>>>(st_sorted, npos, gpos, ori,
                                                   w_ew1t8, eb1, w_wct, bc,
                                                   node_pre, sums, E);
  grid_kernel<<<(G + 127) / 128, 256, 0, stream>>>(sums, counts, mb2, ub1, ub2,
                                                   w_mw2t, w_uw1t, w_uw2t,
                                                   (float*)d_out, G);
}